// Round 4
// baseline (264.343 us; speedup 1.0000x reference)
//
#include <hip/hip_runtime.h>
#include <stdint.h>

// GeAT single-head layer, B=32 N=512 D=128 T=8.
// S_t = X @ (Qw^T a_t) + (Qb a_t);  dst = X@Kw^T+Kb
// VP  = X @ (Pw Vw)^T + Pw Vb      (Pw folded into val projection)
// att_raw[b,n,m] = S_{clamp(e,0)}[b,n,:] . dst[b,m,:] -> mask -> leaky -> softmax
// out = att @ VP + Pb
// Matmuls fp32-emulated: hi/lo bf16 split, 3x mfma_f32_16x16x32_bf16.
// C intermediate stored as raw fp32 (same bytes as hilo, split at stage time).

typedef short bf16x8 __attribute__((ext_vector_type(8)));
typedef float f32x4 __attribute__((ext_vector_type(4)));
typedef unsigned short u16;
typedef unsigned int u32;
typedef unsigned long long u64;

__device__ __forceinline__ u16 f2bf(float x) {
    union { float f; u32 u; } v; v.f = x;
    u32 r = v.u + 0x7FFFu + ((v.u >> 16) & 1u);
    return (u16)(r >> 16);
}
__device__ __forceinline__ float bf2f(u16 h) {
    union { u32 u; float f; } v; v.u = ((u32)h) << 16; return v.f;
}
__device__ __forceinline__ void split_hl(float x, u16& h, u16& l) {
    h = f2bf(x);
    l = f2bf(x - bf2f(h));
}
// split float4 -> packed hi u16x4 and lo u16x4
__device__ __forceinline__ void split4(float4 x, u64& hq, u64& lq) {
    u16 h0, l0, h1, l1, h2, l2, h3, l3;
    split_hl(x.x, h0, l0); split_hl(x.y, h1, l1);
    split_hl(x.z, h2, l2); split_hl(x.w, h3, l3);
    hq = (u64)h0 | ((u64)h1 << 16) | ((u64)h2 << 32) | ((u64)h3 << 48);
    lq = (u64)l0 | ((u64)l1 << 16) | ((u64)l2 << 32) | ((u64)l3 << 48);
}
__device__ __forceinline__ f32x4 mfma16(bf16x8 a, bf16x8 b, f32x4 c) {
    return __builtin_amdgcn_mfma_f32_16x16x32_bf16(a, b, c, 0, 0, 0);
}

// ---------------------------------------------------------------------------
// prep: WcatT (1280 x 128) hi/lo bf16 + bcat (1280) f32.
// rows [0,128): Kw (dst) | [128,256): Pw@Vw (VP) | [256,1280): (Qw^T a_t) cols
// ---------------------------------------------------------------------------
__global__ void prep_kernel(const float* __restrict__ Qw, const float* __restrict__ Qb,
                            const float* __restrict__ Kw, const float* __restrict__ Kb,
                            const float* __restrict__ Vw, const float* __restrict__ Vb,
                            const float* __restrict__ Aa, const float* __restrict__ Pw,
                            u16* __restrict__ WH, u16* __restrict__ WL,
                            float* __restrict__ bcat) {
    int gid = blockIdx.x * 256 + threadIdx.x;
    if (gid >= 1280 * 128) return;
    int j = gid >> 7, d = gid & 127;
    float v, bias = 0.f;
    if (j < 128) { v = Kw[j * 128 + d]; bias = Kb[j]; }
    else if (j < 256) {
        int jj = j - 128;
        float s = 0.f, bs = 0.f;
        for (int k = 0; k < 128; k++) {
            float p = Pw[jj * 128 + k];
            s += p * Vw[k * 128 + d];
            bs += p * Vb[k];
        }
        v = s; bias = bs;
    } else {
        int r = j - 256, t = r >> 7, jj = r & 127;
        float s = 0.f, bs = 0.f;
        for (int e = 0; e < 128; e++) {
            float av = Aa[(e * 128 + jj) * 8 + t];
            s += Qw[e * 128 + d] * av;
            bs += Qb[e] * av;
        }
        v = s; bias = bs;
    }
    u16 h, l; split_hl(v, h, l);
    WH[gid] = h; WL[gid] = l;
    if (d == 0) bcat[j] = bias;
}

// ---------------------------------------------------------------------------
// detect: int32 vs int64 edge layout
// ---------------------------------------------------------------------------
__global__ void detect_kernel(const int* __restrict__ E, int* __restrict__ flag) {
    __shared__ int bad;
    if (threadIdx.x == 0) bad = 0;
    __syncthreads();
    int w0 = E[2 * threadIdx.x + 1];
    int w1 = E[2 * (threadIdx.x + 256) + 1];
    if (!(w0 == 0 || w0 == -1) || !(w1 == 0 || w1 == -1)) atomicOr(&bad, 1);
    __syncthreads();
    if (threadIdx.x == 0) *flag = (bad ? 0 : 1);
}

// ---------------------------------------------------------------------------
// econv: edges -> int8
// ---------------------------------------------------------------------------
__global__ void econv_kernel(const void* __restrict__ E, const int* __restrict__ flag,
                             signed char* __restrict__ E8) {
    int i = (blockIdx.x * 256 + threadIdx.x) * 4;
    char4 o;
    if (*flag) {
        const long long* p = (const long long*)E;
        o.x = (signed char)p[i]; o.y = (signed char)p[i + 1];
        o.z = (signed char)p[i + 2]; o.w = (signed char)p[i + 3];
    } else {
        const int* p = (const int*)E;
        o.x = (signed char)p[i]; o.y = (signed char)p[i + 1];
        o.z = (signed char)p[i + 2]; o.w = (signed char)p[i + 3];
    }
    *(char4*)(E8 + i) = o;
}

// ---------------------------------------------------------------------------
// gemm1 v4: 512 blocks = 256 g-tiles x 2 j-splits (10 j-tiles of 64 each).
// A (X tile) register-resident; W double-buffered in LDS, 1 barrier/tile.
// C tiles: SWAPPED operand order -> acc q maps to j -> direct float4 stores.
// VT tiles: original order -> acc q maps to n -> direct 8B hilo stores.
// ---------------------------------------------------------------------------
__launch_bounds__(256, 2)
__global__ void gemm1_kernel(const float* __restrict__ X,
                             const u16* __restrict__ WH, const u16* __restrict__ WL,
                             const float* __restrict__ bcat,
                             float* __restrict__ C,
                             u16* __restrict__ VTH, u16* __restrict__ VTL) {
    const int id = blockIdx.x;
    const int xcd = id & 7, q5 = id >> 3;
    const int g0 = (xcd * 32 + (q5 >> 1)) * 64;
    const int jbase = (q5 & 1) * 10;
    __shared__ u16 WB[2][2][64 * 128];   // [buf][hi/lo], 64 KB
    const int tid = threadIdx.x;
    const int wid = tid >> 6, lane = tid & 63;
    const int gblk = (wid >> 1) * 32, jblk = (wid & 1) * 32;
    const int lr = lane & 15, lg = lane >> 4;

    // stage A (X tile fp32 -> hi/lo) into WB[1]
    {
        const float4* Xv = (const float4*)(X + (size_t)g0 * 128);
        #pragma unroll
        for (int i = 0; i < 8; i++) {
            int idx = tid + i * 256;
            float4 x = Xv[idx];
            int row = idx >> 5, c4 = idx & 31;
            int boff = (row * 256 + c4 * 8) ^ ((row & 7) << 4);
            u64 hq, lq; split4(x, hq, lq);
            *(u64*)((char*)WB[1][0] + boff) = hq;
            *(u64*)((char*)WB[1][1] + boff) = lq;
        }
    }
    // prefetch W tile 0 into regs
    uint4 nh[4], nl[4];
    {
        const uint4* bh = (const uint4*)(WH + (size_t)(jbase + 0) * 64 * 128);
        const uint4* bl = (const uint4*)(WL + (size_t)(jbase + 0) * 64 * 128);
        #pragma unroll
        for (int i = 0; i < 4; i++) { nh[i] = bh[tid + i * 256]; nl[i] = bl[tid + i * 256]; }
    }
    __syncthreads();
    // A fragments -> registers (reused for all 10 j-tiles)
    bf16x8 afh[4][2], afl[4][2];
    #pragma unroll
    for (int ks = 0; ks < 4; ks++) {
        const int kb2 = (ks * 32 + lg * 8) * 2;
        #pragma unroll
        for (int r = 0; r < 2; r++) {
            int row = gblk + r * 16 + lr;
            int boff = (row * 256 + kb2) ^ ((row & 7) << 4);
            afh[ks][r] = *(const bf16x8*)((const char*)WB[1][0] + boff);
            afl[ks][r] = *(const bf16x8*)((const char*)WB[1][1] + boff);
        }
    }
    // write W tile 0 into WB[0]
    #pragma unroll
    for (int i = 0; i < 4; i++) {
        int idx = tid + i * 256;
        int row = idx >> 4, ch = idx & 15;
        int boff = (row * 256 + ch * 16) ^ ((row & 7) << 4);
        *(uint4*)((char*)WB[0][0] + boff) = nh[i];
        *(uint4*)((char*)WB[0][1] + boff) = nl[i];
    }

    for (int jt = 0; jt < 10; jt++) {
        __syncthreads();
        if (jt < 9) {
            const uint4* bh = (const uint4*)(WH + (size_t)(jbase + jt + 1) * 64 * 128);
            const uint4* bl = (const uint4*)(WL + (size_t)(jbase + jt + 1) * 64 * 128);
            #pragma unroll
            for (int i = 0; i < 4; i++) { nh[i] = bh[tid + i * 256]; nl[i] = bl[tid + i * 256]; }
        }
        const int cur = jt & 1;
        const int j0 = (jbase + jt) * 64;
        const bool valTile = (j0 >= 128 && j0 < 256);
        f32x4 acc[2][2] = {};
        if (valTile) {
            // original order: acc[r=g][c=j], q -> g(n)
            #pragma unroll
            for (int ks = 0; ks < 4; ks++) {
                const int kb2 = (ks * 32 + lg * 8) * 2;
                bf16x8 bfh[2], bfl[2];
                #pragma unroll
                for (int c = 0; c < 2; c++) {
                    int row = jblk + c * 16 + lr;
                    int boff = (row * 256 + kb2) ^ ((row & 7) << 4);
                    bfh[c] = *(const bf16x8*)((const char*)WB[cur][0] + boff);
                    bfl[c] = *(const bf16x8*)((const char*)WB[cur][1] + boff);
                }
                #pragma unroll
                for (int r = 0; r < 2; r++)
                #pragma unroll
                for (int c = 0; c < 2; c++) {
                    acc[r][c] = mfma16(afh[ks][r], bfh[c], acc[r][c]);
                    acc[r][c] = mfma16(afh[ks][r], bfl[c], acc[r][c]);
                    acc[r][c] = mfma16(afl[ks][r], bfh[c], acc[r][c]);
                }
            }
            const int b = g0 >> 9;
            #pragma unroll
            for (int r = 0; r < 2; r++)
            #pragma unroll
            for (int c = 0; c < 2; c++) {
                int j = j0 + jblk + c * 16 + lr;
                float bias = bcat[j];
                int d = j - 128;
                int n = (g0 & 511) + gblk + r * 16 + 4 * lg;
                u64 hq, lq;
                float4 v = {acc[r][c][0] + bias, acc[r][c][1] + bias,
                            acc[r][c][2] + bias, acc[r][c][3] + bias};
                split4(v, hq, lq);
                size_t off = ((size_t)(b * 128 + d)) * 512 + n;
                *(u64*)(VTH + off) = hq;
                *(u64*)(VTL + off) = lq;
            }
        } else {
            // swapped order: acc[c=j][r=g], q -> j
            #pragma unroll
            for (int ks = 0; ks < 4; ks++) {
                const int kb2 = (ks * 32 + lg * 8) * 2;
                bf16x8 bfh[2], bfl[2];
                #pragma unroll
                for (int c = 0; c < 2; c++) {
                    int row = jblk + c * 16 + lr;
                    int boff = (row * 256 + kb2) ^ ((row & 7) << 4);
                    bfh[c] = *(const bf16x8*)((const char*)WB[cur][0] + boff);
                    bfl[c] = *(const bf16x8*)((const char*)WB[cur][1] + boff);
                }
                #pragma unroll
                for (int c = 0; c < 2; c++)
                #pragma unroll
                for (int r = 0; r < 2; r++) {
                    acc[c][r] = mfma16(bfh[c], afh[ks][r], acc[c][r]);
                    acc[c][r] = mfma16(bfh[c], afl[ks][r], acc[c][r]);
                    acc[c][r] = mfma16(bfl[c], afh[ks][r], acc[c][r]);
                }
            }
            #pragma unroll
            for (int c = 0; c < 2; c++)
            #pragma unroll
            for (int r = 0; r < 2; r++) {
                int j = j0 + jblk + c * 16 + 4 * lg;
                int g = g0 + gblk + r * 16 + lr;
                float4 bias4 = *(const float4*)(bcat + j);
                float4 v = {acc[c][r][0] + bias4.x, acc[c][r][1] + bias4.y,
                            acc[c][r][2] + bias4.z, acc[c][r][3] + bias4.w};
                *(float4*)(C + (size_t)g * 1280 + j) = v;
            }
        }
        if (jt < 9) {
            #pragma unroll
            for (int i = 0; i < 4; i++) {
                int idx = tid + i * 256;
                int row = idx >> 4, ch = idx & 15;
                int boff = (row * 256 + ch * 16) ^ ((row & 7) << 4);
                *(uint4*)((char*)WB[cur ^ 1][0] + boff) = nh[i];
                *(uint4*)((char*)WB[cur ^ 1][1] + boff) = nl[i];
            }
        }
    }
}

// ---------------------------------------------------------------------------
// scores: 64n x 128m, 512 thr. fp32 C staged with in-register hilo split.
// dst fragments register-resident across 8 t; A double-buffered; setprio
// around MFMA cluster. XCD swizzle: 4 m-blocks of a (n0,b) share an XCD.
// ---------------------------------------------------------------------------
__launch_bounds__(512, 2)
__global__ void scores_kernel(const float* __restrict__ C,
                              const signed char* __restrict__ E8,
                              float* __restrict__ att) {
    const int id = blockIdx.x;
    const int xcd = id & 7, j = id >> 3;
    const int m0 = (j & 3) * 128;
    const int pair = xcd * 32 + (j >> 2);
    const int n0 = (pair & 7) * 64, b = pair >> 3;
    __shared__ u16 BH[128 * 128], BL[128 * 128];
    __shared__ u16 AH[2][64 * 128], AL[2][64 * 128];
    const int tid = threadIdx.x;
    const int wid = tid >> 6, lane = tid & 63;
    const int wr = (wid >> 2) * 32, wc = (wid & 3) * 32;
    const int lr = lane & 15, lg = lane >> 4;

    // stage B = dst rows m0..m0+127 (fp32 -> hilo)
    #pragma unroll
    for (int i = 0; i < 8; i++) {
        int idx = tid + i * 512;
        int row = idx >> 5, c4 = idx & 31;
        float4 x = *(const float4*)(C + (size_t)(b * 512 + m0 + row) * 1280 + c4 * 4);
        u64 hq, lq; split4(x, hq, lq);
        int boff = (row * 256 + c4 * 8) ^ ((row & 7) << 4);
        *(u64*)((char*)BH + boff) = hq;
        *(u64*)((char*)BL + boff) = lq;
    }
    int ed[2][2][4];
    #pragma unroll
    for (int r = 0; r < 2; r++)
    #pragma unroll
    for (int c = 0; c < 2; c++)
    #pragma unroll
    for (int q = 0; q < 4; q++) {
        int n = n0 + wr + r * 16 + 4 * lg + q;
        int m = m0 + wc + c * 16 + lr;
        ed[r][c][q] = E8[((size_t)b * 512 + n) * 512 + m];
    }
    // stage A(t=0)
    {
        #pragma unroll
        for (int i = 0; i < 4; i++) {
            int idx = tid + i * 512;
            int row = idx >> 5, c4 = idx & 31;
            float4 x = *(const float4*)(C + (size_t)(b * 512 + n0 + row) * 1280 + 256 + c4 * 4);
            u64 hq, lq; split4(x, hq, lq);
            int boff = (row * 256 + c4 * 8) ^ ((row & 7) << 4);
            *(u64*)((char*)AH[0] + boff) = hq;
            *(u64*)((char*)AL[0] + boff) = lq;
        }
    }
    __syncthreads();
    bf16x8 bfh[4][2], bfl[4][2];
    #pragma unroll
    for (int ks = 0; ks < 4; ks++) {
        const int kb2 = (ks * 32 + lg * 8) * 2;
        #pragma unroll
        for (int c = 0; c < 2; c++) {
            int row = wc + c * 16 + lr;
            int boff = (row * 256 + kb2) ^ ((row & 7) << 4);
            bfh[ks][c] = *(const bf16x8*)((const char*)BH + boff);
            bfl[ks][c] = *(const bf16x8*)((const char*)BL + boff);
        }
    }
    float sel[2][2][4];
    #pragma unroll
    for (int r = 0; r < 2; r++)
    #pragma unroll
    for (int c = 0; c < 2; c++)
    #pragma unroll
    for (int q = 0; q < 4; q++) sel[r][c][q] = 0.f;

    for (int t = 0; t < 8; t++) {
        const int cur = t & 1;
        float4 nx[4];
        if (t < 7) {                       // issue next-t loads early
            #pragma unroll
            for (int i = 0; i < 4; i++) {
                int idx = tid + i * 512;
                int row = idx >> 5, c4 = idx & 31;
                nx[i] = *(const float4*)(C + (size_t)(b * 512 + n0 + row) * 1280
                                           + 256 + (t + 1) * 128 + c4 * 4);
            }
        }
        f32x4 acc[2][2] = {};
        __builtin_amdgcn_s_setprio(1);
        #pragma unroll
        for (int ks = 0; ks < 4; ks++) {
            const int kb2 = (ks * 32 + lg * 8) * 2;
            bf16x8 afh[2], afl[2];
            #pragma unroll
            for (int r = 0; r < 2; r++) {
                int row = wr + r * 16 + lr;
                int boff = (row * 256 + kb2) ^ ((row & 7) << 4);
                afh[r] = *(const bf16x8*)((const char*)AH[cur] + boff);
                afl[r] = *(const bf16x8*)((const char*)AL[cur] + boff);
            }
            #pragma unroll
            for (int r = 0; r < 2; r++)
            #pragma unroll
            for (int c = 0; c < 2; c++) {
                acc[r][c] = mfma16(afh[r], bfh[ks][c], acc[r][c]);
                acc[r][c] = mfma16(afh[r], bfl[ks][c], acc[r][c]);
                acc[r][c] = mfma16(afl[r], bfh[ks][c], acc[r][c]);
            }
        }
        __builtin_amdgcn_s_setprio(0);
        #pragma unroll
        for (int r = 0; r < 2; r++)
        #pragma unroll
        for (int c = 0; c < 2; c++)
        #pragma unroll
        for (int q = 0; q < 4; q++) {
            int ec = ed[r][c][q] < 0 ? 0 : ed[r][c][q];
            sel[r][c][q] = (ec == t) ? acc[r][c][q] : sel[r][c][q];
        }
        if (t < 7) {                       // split + land prefetch
            #pragma unroll
            for (int i = 0; i < 4; i++) {
                int idx = tid + i * 512;
                int row = idx >> 5, c4 = idx & 31;
                u64 hq, lq; split4(nx[i], hq, lq);
                int boff = (row * 256 + c4 * 8) ^ ((row & 7) << 4);
                *(u64*)((char*)AH[cur ^ 1] + boff) = hq;
                *(u64*)((char*)AL[cur ^ 1] + boff) = lq;
            }
        }
        __syncthreads();
    }
    #pragma unroll
    for (int r = 0; r < 2; r++)
    #pragma unroll
    for (int c = 0; c < 2; c++)
    #pragma unroll
    for (int q = 0; q < 4; q++) {
        float v = (ed[r][c][q] == -1) ? -1e10f : sel[r][c][q];
        v = (v >= 0.f) ? v : 0.2f * v;
        size_t n = n0 + wr + r * 16 + 4 * lg + q;
        size_t m = m0 + wc + c * 16 + lr;
        att[((size_t)b * 512 + n) * 512 + m] = v;
    }
}

// ---------------------------------------------------------------------------
// out: fused softmax + (att @ VP) + Pb. att row-slice register-resident.
// ---------------------------------------------------------------------------
__launch_bounds__(256, 2)
__global__ void out_kernel(const float* __restrict__ att,
                           const u16* __restrict__ VTH, const u16* __restrict__ VTL,
                           const float* __restrict__ Pb, float* __restrict__ out) {
    const int id = blockIdx.x;
    const int xcd = id & 7, j = id >> 3;
    const int b = xcd * 4 + (j >> 4);
    const int n0 = (j & 15) * 32;
    __shared__ u16 PH[32 * 64], PL[32 * 64];
    __shared__ u16 VH[128 * 64], VL[128 * 64];
    const int tid = threadIdx.x;
    const int row = tid >> 3, c8 = tid & 7;
    float4 av0[8], av1[8];
    const float4* rp = (const float4*)(att + ((size_t)b * 512 + n0 + row) * 512);
    #pragma unroll
    for (int mc = 0; mc < 8; mc++) {
        av0[mc] = rp[mc * 16 + c8 * 2];
        av1[mc] = rp[mc * 16 + c8 * 2 + 1];
    }
    float mx = -1e30f;
    #pragma unroll
    for (int mc = 0; mc < 8; mc++) {
        mx = fmaxf(mx, fmaxf(fmaxf(fmaxf(av0[mc].x, av0[mc].y), fmaxf(av0[mc].z, av0[mc].w)),
                             fmaxf(fmaxf(av1[mc].x, av1[mc].y), fmaxf(av1[mc].z, av1[mc].w))));
    }
    #pragma unroll
    for (int o = 1; o < 8; o <<= 1) mx = fmaxf(mx, __shfl_xor(mx, o, 64));
    float s = 0.f;
    #pragma unroll
    for (int mc = 0; mc < 8; mc++) {
        av0[mc].x = expf(av0[mc].x - mx); av0[mc].y = expf(av0[mc].y - mx);
        av0[mc].z = expf(av0[mc].z - mx); av0[mc].w = expf(av0[mc].w - mx);
        av1[mc].x = expf(av1[mc].x - mx); av1[mc].y = expf(av1[mc].y - mx);
        av1[mc].z = expf(av1[mc].z - mx); av1[mc].w = expf(av1[mc].w - mx);
        s += av0[mc].x + av0[mc].y + av0[mc].z + av0[mc].w
           + av1[mc].x + av1[mc].y + av1[mc].z + av1[mc].w;
    }
    #pragma unroll
    for (int o = 1; o < 8; o <<= 1) s += __shfl_xor(s, o, 64);
    const float inv = 1.0f / s;
    const int wid = tid >> 6, lane = tid & 63;
    const int lr = lane & 15, lg = lane >> 4;
    const int wc = wid * 32;
    f32x4 acc[2][2] = {};
    for (int mc = 0; mc < 8; mc++) {
        {
            float4 p0 = {av0[mc].x * inv, av0[mc].y * inv, av0[mc].z * inv, av0[mc].w * inv};
            float4 p1 = {av1[mc].x * inv, av1[mc].y * inv, av1[mc].z * inv, av1[mc].w * inv};
            u64 h0, l0, h1, l1;
            split4(p0, h0, l0); split4(p1, h1, l1);
            int boff = (row * 128 + c8 * 16) ^ ((row & 7) << 4);
            *(u64*)((char*)PH + boff) = h0;
            *(u64*)((char*)PH + boff + 8) = h1;
            *(u64*)((char*)PL + boff) = l0;
            *(u64*)((char*)PL + boff + 8) = l1;
        }
        #pragma unroll
        for (int i = 0; i < 4; i++) {
            int idx = tid + i * 256;
            int vrow = idx >> 3, ch = idx & 7;
            size_t src = ((size_t)(b * 128 + vrow)) * 512 + mc * 64;
            int boff = (vrow * 128 + ch * 16) ^ ((vrow & 7) << 4);
            *(uint4*)((char*)VH + boff) = ((const uint4*)(VTH + src))[ch];
            *(uint4*)((char*)VL + boff) = ((const uint4*)(VTL + src))[ch];
        }
        __syncthreads();
        #pragma unroll
        for (int ks = 0; ks < 2; ks++) {
            const int kb2 = (ks * 32 + lg * 8) * 2;
            bf16x8 ah[2], al[2];
            #pragma unroll
            for (int r = 0; r < 2; r++) {
                int prow = r * 16 + lr;
                int boff = (prow * 128 + kb2) ^ ((prow & 7) << 4);
                ah[r] = *(const bf16x8*)((const char*)PH + boff);
                al[r] = *(const bf16x8*)((const char*)PL + boff);
            }
            #pragma unroll
            for (int c = 0; c < 2; c++) {
                int vrow = wc + c * 16 + lr;
                int boff = (vrow * 128 + kb2) ^ ((vrow & 7) << 4);
                bf16x8 bh = *(const bf16x8*)((const char*)VH + boff);
                bf16x8 bl = *(const bf16x8*)((const char*)VL + boff);
                #pragma unroll
                for (int r = 0; r < 2; r++) {
                    acc[r][c] = mfma16(ah[r], bh, acc[r][c]);
                    acc[r][c] = mfma16(ah[r], bl, acc[r][c]);
                    acc[r][c] = mfma16(al[r], bh, acc[r][c]);
                }
            }
        }
        __syncthreads();
    }
    #pragma unroll
    for (int r = 0; r < 2; r++)
    #pragma unroll
    for (int c = 0; c < 2; c++)
    #pragma unroll
    for (int q = 0; q < 4; q++) {
        int n = n0 + r * 16 + 4 * lg + q;
        int d = wc + c * 16 + lr;
        out[((size_t)b * 512 + n) * 128 + d] = acc[r][c][q] + Pb[d];
    }
}

extern "C" void kernel_launch(void* const* d_in, const int* in_sizes, int n_in,
                              void* d_out, int out_size, void* d_ws, size_t ws_size,
                              hipStream_t stream) {
    (void)in_sizes; (void)n_in; (void)out_size; (void)ws_size;
    const float* X  = (const float*)d_in[0];
    const void*  E  = d_in[1];
    const float* Qw = (const float*)d_in[2];
    const float* Qb = (const float*)d_in[3];
    const float* Kw = (const float*)d_in[4];
    const float* Kb = (const float*)d_in[5];
    const float* Vw = (const float*)d_in[6];
    const float* Vb = (const float*)d_in[7];
    const float* Aa = (const float*)d_in[8];
    const float* Pw = (const float*)d_in[9];
    const float* Pb = (const float*)d_in[10];
    float* out = (float*)d_out;

    char* ws = (char*)d_ws;
    size_t cur = 0;
    auto alloc = [&](size_t bytes) -> char* {
        char* p = ws + cur;
        cur += (bytes + 255) & ~(size_t)255;
        return p;
    };
    int*   flag = (int*)  alloc(4);
    u16*   WH   = (u16*)  alloc((size_t)1280 * 128 * 2);
    u16*   WL   = (u16*)  alloc((size_t)1280 * 128 * 2);
    float* bcat = (float*)alloc(1280 * 4);
    float* C    = (float*)alloc((size_t)16384 * 1280 * 4);
    u16*   VTH  = (u16*)  alloc((size_t)32 * 128 * 512 * 2);
    u16*   VTL  = (u16*)  alloc((size_t)32 * 128 * 512 * 2);
    float* att  = (float*)alloc((size_t)32 * 512 * 512 * 4);
    signed char* E8 = (signed char*)alloc((size_t)32 * 512 * 512);

    prep_kernel<<<640, 256, 0, stream>>>(Qw, Qb, Kw, Kb, Vw, Vb, Aa, Pw, WH, WL, bcat);
    detect_kernel<<<1, 256, 0, stream>>>((const int*)E, flag);
    econv_kernel<<<8192, 256, 0, stream>>>(E, flag, E8);
    gemm1_kernel<<<512, 256, 0, stream>>>(X, WH, WL, bcat, C, VTH, VTL);
    scores_kernel<<<1024, 512, 0, stream>>>(C, E8, att);
    out_kernel<<<512, 256, 0, stream>>>(att, VTH, VTL, Pb, out);
}

// Round 5
// 221.315 us; speedup vs baseline: 1.1944x; 1.1944x over previous
//
#include <hip/hip_runtime.h>
#include <stdint.h>

// GeAT single-head layer, B=32 N=512 D=128 T=8.
// S_t = X @ (Qw^T a_t) + (Qb a_t);  dst = X@Kw^T+Kb
// VP  = X @ (Pw Vw)^T + Pw Vb      (Pw folded into val projection)
// att_raw[b,n,m] = S_{clamp(e,0)}[b,n,:] . dst[b,m,:] -> mask -> leaky -> softmax
// out = att @ VP + Pb
// Matmuls fp32-emulated: hi/lo bf16 split, 3x mfma_f32_16x16x32_bf16.
// gemm1 is LDS-free/barrier-free: W is pre-swizzled to fragment-linear layout
// so wave fragment loads are 1KB-contiguous L2 reads.

typedef short bf16x8 __attribute__((ext_vector_type(8)));
typedef float f32x4 __attribute__((ext_vector_type(4)));
typedef unsigned short u16;
typedef unsigned int u32;
typedef unsigned long long u64;

__device__ __forceinline__ u16 f2bf(float x) {
    union { float f; u32 u; } v; v.f = x;
    u32 r = v.u + 0x7FFFu + ((v.u >> 16) & 1u);
    return (u16)(r >> 16);
}
__device__ __forceinline__ float bf2f(u16 h) {
    union { u32 u; float f; } v; v.u = ((u32)h) << 16; return v.f;
}
__device__ __forceinline__ void split_hl(float x, u16& h, u16& l) {
    h = f2bf(x);
    l = f2bf(x - bf2f(h));
}
__device__ __forceinline__ void split4(float4 x, u64& hq, u64& lq) {
    u16 h0, l0, h1, l1, h2, l2, h3, l3;
    split_hl(x.x, h0, l0); split_hl(x.y, h1, l1);
    split_hl(x.z, h2, l2); split_hl(x.w, h3, l3);
    hq = (u64)h0 | ((u64)h1 << 16) | ((u64)h2 << 32) | ((u64)h3 << 48);
    lq = (u64)l0 | ((u64)l1 << 16) | ((u64)l2 << 32) | ((u64)l3 << 48);
}
// split 8 consecutive fp32 into hi/lo bf16x8 fragments
__device__ __forceinline__ void split8(float4 a, float4 b, bf16x8& h8, bf16x8& l8) {
    u16 hh[8], ll[8];
    split_hl(a.x, hh[0], ll[0]); split_hl(a.y, hh[1], ll[1]);
    split_hl(a.z, hh[2], ll[2]); split_hl(a.w, hh[3], ll[3]);
    split_hl(b.x, hh[4], ll[4]); split_hl(b.y, hh[5], ll[5]);
    split_hl(b.z, hh[6], ll[6]); split_hl(b.w, hh[7], ll[7]);
    #pragma unroll
    for (int i = 0; i < 8; i++) { h8[i] = (short)hh[i]; l8[i] = (short)ll[i]; }
}
__device__ __forceinline__ f32x4 mfma16(bf16x8 a, bf16x8 b, f32x4 c) {
    return __builtin_amdgcn_mfma_f32_16x16x32_bf16(a, b, c, 0, 0, 0);
}

// ---------------------------------------------------------------------------
// prep: Wcat (1280 x 128) -> fragment-linear hi/lo bf16 WFH/WFL + bcat f32.
// j rows: [0,128): Kw (dst) | [128,256): Pw@Vw (VP) | [256,1280): (Qw^T a_t)
// WF index: ((jg*16 + kc)*16 + (j&15))*8 + (d&7), jg=j>>4, kc=d>>3.
// ---------------------------------------------------------------------------
__global__ void prep_kernel(const float* __restrict__ Qw, const float* __restrict__ Qb,
                            const float* __restrict__ Kw, const float* __restrict__ Kb,
                            const float* __restrict__ Vw, const float* __restrict__ Vb,
                            const float* __restrict__ Aa, const float* __restrict__ Pw,
                            u16* __restrict__ WFH, u16* __restrict__ WFL,
                            float* __restrict__ bcat) {
    int gid = blockIdx.x * 256 + threadIdx.x;
    if (gid >= 1280 * 128) return;
    int j = gid >> 7, d = gid & 127;
    float v, bias = 0.f;
    if (j < 128) { v = Kw[j * 128 + d]; bias = Kb[j]; }
    else if (j < 256) {
        int jj = j - 128;
        float s = 0.f, bs = 0.f;
        for (int k = 0; k < 128; k++) {
            float p = Pw[jj * 128 + k];
            s += p * Vw[k * 128 + d];
            bs += p * Vb[k];
        }
        v = s; bias = bs;
    } else {
        int r = j - 256, t = r >> 7, jj = r & 127;
        float s = 0.f, bs = 0.f;
        for (int e = 0; e < 128; e++) {
            float av = Aa[(e * 128 + jj) * 8 + t];
            s += Qw[e * 128 + d] * av;
            bs += Qb[e] * av;
        }
        v = s; bias = bs;
    }
    u16 h, l; split_hl(v, h, l);
    size_t idx = ((size_t)((j >> 4) * 16 + (d >> 3)) * 16 + (j & 15)) * 8 + (d & 7);
    WFH[idx] = h; WFL[idx] = l;
    if (d == 0) bcat[j] = bias;
}

// ---------------------------------------------------------------------------
// detect: int32 vs int64 edge layout (odd words of int64 small values are 0/-1)
// ---------------------------------------------------------------------------
__global__ void detect_kernel(const int* __restrict__ E, int* __restrict__ flag) {
    __shared__ int bad;
    if (threadIdx.x == 0) bad = 0;
    __syncthreads();
    int w0 = E[2 * threadIdx.x + 1];
    int w1 = E[2 * (threadIdx.x + 256) + 1];
    if (!(w0 == 0 || w0 == -1) || !(w1 == 0 || w1 == -1)) atomicOr(&bad, 1);
    __syncthreads();
    if (threadIdx.x == 0) *flag = (bad ? 0 : 1);
}

// ---------------------------------------------------------------------------
// gemm1 v5: LDS-free, barrier-free. 1024 blocks = 256 g-tiles x 4 j-splits
// (5 j-tiles of 64 each). A (X tile) register-resident from direct global
// reads; W fragments read directly from fragment-linear WFH/WFL (L2-hot,
// 1KB contiguous per wave-load). No __shared__, no __syncthreads.
// C tiles: swapped operand order -> acc q maps to j -> direct float4 stores.
// VT tiles: original order -> acc q maps to n -> direct 8B hilo stores.
// ---------------------------------------------------------------------------
__launch_bounds__(256, 3)
__global__ void gemm1_kernel(const float* __restrict__ X,
                             const u16* __restrict__ WFH, const u16* __restrict__ WFL,
                             const float* __restrict__ bcat,
                             float* __restrict__ C,
                             u16* __restrict__ VTH, u16* __restrict__ VTL) {
    const int id = blockIdx.x;
    const int xcd = id & 7, q = id >> 3;           // q 0..127
    const int g0 = (xcd * 32 + (q >> 2)) * 64;     // 256 g-tiles, XCD-chunked
    const int jsplit = q & 3;                      // j-tiles jsplit*5 .. +4
    const int tid = threadIdx.x;
    const int wid = tid >> 6, lane = tid & 63;
    const int gblk = (wid >> 1) * 32, jblk = (wid & 1) * 32;
    const int lr = lane & 15, lg = lane >> 4;

    // A fragments: direct global read of X tile, hilo split, register-resident
    bf16x8 afh[4][2], afl[4][2];
    #pragma unroll
    for (int ks = 0; ks < 4; ks++)
    #pragma unroll
    for (int r = 0; r < 2; r++) {
        const float* p = X + (size_t)(g0 + gblk + r * 16 + lr) * 128 + ks * 32 + lg * 8;
        float4 a = *(const float4*)p;
        float4 b = *(const float4*)(p + 4);
        split8(a, b, afh[ks][r], afl[ks][r]);
    }

    #pragma unroll
    for (int jt5 = 0; jt5 < 5; jt5++) {
        const int jt = jsplit * 5 + jt5;
        const int j0 = jt * 64;
        const bool valTile = (jt == 2 || jt == 3);
        const int jgbase = (j0 + jblk) >> 4;
        f32x4 acc[2][2] = {};
        if (valTile) {
            // original order: acc[r=g][c=j], q -> g(n)
            #pragma unroll
            for (int ks = 0; ks < 4; ks++) {
                bf16x8 bfh[2], bfl[2];
                #pragma unroll
                for (int c = 0; c < 2; c++) {
                    size_t eo = ((size_t)((jgbase + c) * 16 + ks * 4 + lg) * 16 + lr) * 8;
                    bfh[c] = *(const bf16x8*)(WFH + eo);
                    bfl[c] = *(const bf16x8*)(WFL + eo);
                }
                #pragma unroll
                for (int r = 0; r < 2; r++)
                #pragma unroll
                for (int c = 0; c < 2; c++) {
                    acc[r][c] = mfma16(afh[ks][r], bfh[c], acc[r][c]);
                    acc[r][c] = mfma16(afh[ks][r], bfl[c], acc[r][c]);
                    acc[r][c] = mfma16(afl[ks][r], bfh[c], acc[r][c]);
                }
            }
            const int b = g0 >> 9;
            #pragma unroll
            for (int r = 0; r < 2; r++)
            #pragma unroll
            for (int c = 0; c < 2; c++) {
                int j = j0 + jblk + c * 16 + lr;
                float bias = bcat[j];
                int d = j - 128;
                int n = (g0 & 511) + gblk + r * 16 + 4 * lg;
                float4 v = {acc[r][c][0] + bias, acc[r][c][1] + bias,
                            acc[r][c][2] + bias, acc[r][c][3] + bias};
                u64 hq, lq; split4(v, hq, lq);
                size_t off = ((size_t)(b * 128 + d)) * 512 + n;
                *(u64*)(VTH + off) = hq;
                *(u64*)(VTL + off) = lq;
            }
        } else {
            // swapped order: acc[c=j][r=g], q -> j
            #pragma unroll
            for (int ks = 0; ks < 4; ks++) {
                bf16x8 bfh[2], bfl[2];
                #pragma unroll
                for (int c = 0; c < 2; c++) {
                    size_t eo = ((size_t)((jgbase + c) * 16 + ks * 4 + lg) * 16 + lr) * 8;
                    bfh[c] = *(const bf16x8*)(WFH + eo);
                    bfl[c] = *(const bf16x8*)(WFL + eo);
                }
                #pragma unroll
                for (int c = 0; c < 2; c++)
                #pragma unroll
                for (int r = 0; r < 2; r++) {
                    acc[c][r] = mfma16(bfh[c], afh[ks][r], acc[c][r]);
                    acc[c][r] = mfma16(bfh[c], afl[ks][r], acc[c][r]);
                    acc[c][r] = mfma16(bfl[c], afh[ks][r], acc[c][r]);
                }
            }
            #pragma unroll
            for (int c = 0; c < 2; c++)
            #pragma unroll
            for (int r = 0; r < 2; r++) {
                int j = j0 + jblk + c * 16 + 4 * lg;
                int g = g0 + gblk + r * 16 + lr;
                float4 bias4 = *(const float4*)(bcat + j);
                float4 v = {acc[c][r][0] + bias4.x, acc[c][r][1] + bias4.y,
                            acc[c][r][2] + bias4.z, acc[c][r][3] + bias4.w};
                *(float4*)(C + (size_t)g * 1280 + j) = v;
            }
        }
    }
}

// ---------------------------------------------------------------------------
// scores: 64n x 128m, 512 thr. fp32 C staged with in-register hilo split.
// Edges read DIRECTLY (int32/int64 uniform branch; no econv pass).
// dst fragments register-resident across 8 t; A double-buffered; setprio
// around MFMA cluster. XCD swizzle: 4 m-blocks of a (n0,b) share an XCD.
// ---------------------------------------------------------------------------
__launch_bounds__(512, 2)
__global__ void scores_kernel(const float* __restrict__ C,
                              const void* __restrict__ Eptr, const int* __restrict__ flag,
                              float* __restrict__ att) {
    const int id = blockIdx.x;
    const int xcd = id & 7, j = id >> 3;
    const int m0 = (j & 3) * 128;
    const int pair = xcd * 32 + (j >> 2);
    const int n0 = (pair & 7) * 64, b = pair >> 3;
    __shared__ u16 BH[128 * 128], BL[128 * 128];
    __shared__ u16 AH[2][64 * 128], AL[2][64 * 128];
    const int tid = threadIdx.x;
    const int wid = tid >> 6, lane = tid & 63;
    const int wr = (wid >> 2) * 32, wc = (wid & 3) * 32;
    const int lr = lane & 15, lg = lane >> 4;
    const bool e64 = (*flag != 0);

    // stage B = dst rows m0..m0+127 (fp32 -> hilo)
    #pragma unroll
    for (int i = 0; i < 8; i++) {
        int idx = tid + i * 512;
        int row = idx >> 5, c4 = idx & 31;
        float4 x = *(const float4*)(C + (size_t)(b * 512 + m0 + row) * 1280 + c4 * 4);
        u64 hq, lq; split4(x, hq, lq);
        int boff = (row * 256 + c4 * 8) ^ ((row & 7) << 4);
        *(u64*)((char*)BH + boff) = hq;
        *(u64*)((char*)BL + boff) = lq;
    }
    int ed[2][2][4];
    #pragma unroll
    for (int r = 0; r < 2; r++)
    #pragma unroll
    for (int c = 0; c < 2; c++)
    #pragma unroll
    for (int q = 0; q < 4; q++) {
        size_t n = n0 + wr + r * 16 + 4 * lg + q;
        size_t m = m0 + wc + c * 16 + lr;
        size_t idx = ((size_t)b * 512 + n) * 512 + m;
        ed[r][c][q] = e64 ? (int)((const long long*)Eptr)[idx] : ((const int*)Eptr)[idx];
    }
    // stage A(t=0)
    {
        #pragma unroll
        for (int i = 0; i < 4; i++) {
            int idx = tid + i * 512;
            int row = idx >> 5, c4 = idx & 31;
            float4 x = *(const float4*)(C + (size_t)(b * 512 + n0 + row) * 1280 + 256 + c4 * 4);
            u64 hq, lq; split4(x, hq, lq);
            int boff = (row * 256 + c4 * 8) ^ ((row & 7) << 4);
            *(u64*)((char*)AH[0] + boff) = hq;
            *(u64*)((char*)AL[0] + boff) = lq;
        }
    }
    __syncthreads();
    bf16x8 bfh[4][2], bfl[4][2];
    #pragma unroll
    for (int ks = 0; ks < 4; ks++) {
        const int kb2 = (ks * 32 + lg * 8) * 2;
        #pragma unroll
        for (int c = 0; c < 2; c++) {
            int row = wc + c * 16 + lr;
            int boff = (row * 256 + kb2) ^ ((row & 7) << 4);
            bfh[ks][c] = *(const bf16x8*)((const char*)BH + boff);
            bfl[ks][c] = *(const bf16x8*)((const char*)BL + boff);
        }
    }
    float sel[2][2][4];
    #pragma unroll
    for (int r = 0; r < 2; r++)
    #pragma unroll
    for (int c = 0; c < 2; c++)
    #pragma unroll
    for (int q = 0; q < 4; q++) sel[r][c][q] = 0.f;

    for (int t = 0; t < 8; t++) {
        const int cur = t & 1;
        float4 nx[4];
        if (t < 7) {                       // issue next-t loads early
            #pragma unroll
            for (int i = 0; i < 4; i++) {
                int idx = tid + i * 512;
                int row = idx >> 5, c4 = idx & 31;
                nx[i] = *(const float4*)(C + (size_t)(b * 512 + n0 + row) * 1280
                                           + 256 + (t + 1) * 128 + c4 * 4);
            }
        }
        f32x4 acc[2][2] = {};
        __builtin_amdgcn_s_setprio(1);
        #pragma unroll
        for (int ks = 0; ks < 4; ks++) {
            const int kb2 = (ks * 32 + lg * 8) * 2;
            bf16x8 afh[2], afl[2];
            #pragma unroll
            for (int r = 0; r < 2; r++) {
                int row = wr + r * 16 + lr;
                int boff = (row * 256 + kb2) ^ ((row & 7) << 4);
                afh[r] = *(const bf16x8*)((const char*)AH[cur] + boff);
                afl[r] = *(const bf16x8*)((const char*)AL[cur] + boff);
            }
            #pragma unroll
            for (int r = 0; r < 2; r++)
            #pragma unroll
            for (int c = 0; c < 2; c++) {
                acc[r][c] = mfma16(afh[r], bfh[ks][c], acc[r][c]);
                acc[r][c] = mfma16(afh[r], bfl[ks][c], acc[r][c]);
                acc[r][c] = mfma16(afl[r], bfh[ks][c], acc[r][c]);
            }
        }
        __builtin_amdgcn_s_setprio(0);
        #pragma unroll
        for (int r = 0; r < 2; r++)
        #pragma unroll
        for (int c = 0; c < 2; c++)
        #pragma unroll
        for (int q = 0; q < 4; q++) {
            int ec = ed[r][c][q] < 0 ? 0 : ed[r][c][q];
            sel[r][c][q] = (ec == t) ? acc[r][c][q] : sel[r][c][q];
        }
        if (t < 7) {                       // split + land prefetch
            #pragma unroll
            for (int i = 0; i < 4; i++) {
                int idx = tid + i * 512;
                int row = idx >> 5, c4 = idx & 31;
                u64 hq, lq; split4(nx[i], hq, lq);
                int boff = (row * 256 + c4 * 8) ^ ((row & 7) << 4);
                *(u64*)((char*)AH[cur ^ 1] + boff) = hq;
                *(u64*)((char*)AL[cur ^ 1] + boff) = lq;
            }
        }
        __syncthreads();
    }
    #pragma unroll
    for (int r = 0; r < 2; r++)
    #pragma unroll
    for (int c = 0; c < 2; c++)
    #pragma unroll
    for (int q = 0; q < 4; q++) {
        float v = (ed[r][c][q] == -1) ? -1e10f : sel[r][c][q];
        v = (v >= 0.f) ? v : 0.2f * v;
        size_t n = n0 + wr + r * 16 + 4 * lg + q;
        size_t m = m0 + wc + c * 16 + lr;
        att[((size_t)b * 512 + n) * 512 + m] = v;
    }
}

// ---------------------------------------------------------------------------
// out: fused softmax + (att @ VP) + Pb. att row-slice register-resident.
// ---------------------------------------------------------------------------
__launch_bounds__(256, 2)
__global__ void out_kernel(const float* __restrict__ att,
                           const u16* __restrict__ VTH, const u16* __restrict__ VTL,
                           const float* __restrict__ Pb, float* __restrict__ out) {
    const int id = blockIdx.x;
    const int xcd = id & 7, j = id >> 3;
    const int b = xcd * 4 + (j >> 4);
    const int n0 = (j & 15) * 32;
    __shared__ u16 PH[32 * 64], PL[32 * 64];
    __shared__ u16 VH[128 * 64], VL[128 * 64];
    const int tid = threadIdx.x;
    const int row = tid >> 3, c8 = tid & 7;
    float4 av0[8], av1[8];
    const float4* rp = (const float4*)(att + ((size_t)b * 512 + n0 + row) * 512);
    #pragma unroll
    for (int mc = 0; mc < 8; mc++) {
        av0[mc] = rp[mc * 16 + c8 * 2];
        av1[mc] = rp[mc * 16 + c8 * 2 + 1];
    }
    float mx = -1e30f;
    #pragma unroll
    for (int mc = 0; mc < 8; mc++) {
        mx = fmaxf(mx, fmaxf(fmaxf(fmaxf(av0[mc].x, av0[mc].y), fmaxf(av0[mc].z, av0[mc].w)),
                             fmaxf(fmaxf(av1[mc].x, av1[mc].y), fmaxf(av1[mc].z, av1[mc].w))));
    }
    #pragma unroll
    for (int o = 1; o < 8; o <<= 1) mx = fmaxf(mx, __shfl_xor(mx, o, 64));
    float s = 0.f;
    #pragma unroll
    for (int mc = 0; mc < 8; mc++) {
        av0[mc].x = expf(av0[mc].x - mx); av0[mc].y = expf(av0[mc].y - mx);
        av0[mc].z = expf(av0[mc].z - mx); av0[mc].w = expf(av0[mc].w - mx);
        av1[mc].x = expf(av1[mc].x - mx); av1[mc].y = expf(av1[mc].y - mx);
        av1[mc].z = expf(av1[mc].z - mx); av1[mc].w = expf(av1[mc].w - mx);
        s += av0[mc].x + av0[mc].y + av0[mc].z + av0[mc].w
           + av1[mc].x + av1[mc].y + av1[mc].z + av1[mc].w;
    }
    #pragma unroll
    for (int o = 1; o < 8; o <<= 1) s += __shfl_xor(s, o, 64);
    const float inv = 1.0f / s;
    const int wid = tid >> 6, lane = tid & 63;
    const int lr = lane & 15, lg = lane >> 4;
    const int wc = wid * 32;
    f32x4 acc[2][2] = {};
    for (int mc = 0; mc < 8; mc++) {
        {
            float4 p0 = {av0[mc].x * inv, av0[mc].y * inv, av0[mc].z * inv, av0[mc].w * inv};
            float4 p1 = {av1[mc].x * inv, av1[mc].y * inv, av1[mc].z * inv, av1[mc].w * inv};
            u64 h0, l0, h1, l1;
            split4(p0, h0, l0); split4(p1, h1, l1);
            int boff = (row * 128 + c8 * 16) ^ ((row & 7) << 4);
            *(u64*)((char*)PH + boff) = h0;
            *(u64*)((char*)PH + boff + 8) = h1;
            *(u64*)((char*)PL + boff) = l0;
            *(u64*)((char*)PL + boff + 8) = l1;
        }
        #pragma unroll
        for (int i = 0; i < 4; i++) {
            int idx = tid + i * 256;
            int vrow = idx >> 3, ch = idx & 7;
            size_t src = ((size_t)(b * 128 + vrow)) * 512 + mc * 64;
            int boff = (vrow * 128 + ch * 16) ^ ((vrow & 7) << 4);
            *(uint4*)((char*)VH + boff) = ((const uint4*)(VTH + src))[ch];
            *(uint4*)((char*)VL + boff) = ((const uint4*)(VTL + src))[ch];
        }
        __syncthreads();
        #pragma unroll
        for (int ks = 0; ks < 2; ks++) {
            const int kb2 = (ks * 32 + lg * 8) * 2;
            bf16x8 ah[2], al[2];
            #pragma unroll
            for (int r = 0; r < 2; r++) {
                int prow = r * 16 + lr;
                int boff = (prow * 128 + kb2) ^ ((prow & 7) << 4);
                ah[r] = *(const bf16x8*)((const char*)PH + boff);
                al[r] = *(const bf16x8*)((const char*)PL + boff);
            }
            #pragma unroll
            for (int c = 0; c < 2; c++) {
                int vrow = wc + c * 16 + lr;
                int boff = (vrow * 128 + kb2) ^ ((vrow & 7) << 4);
                bf16x8 bh = *(const bf16x8*)((const char*)VH + boff);
                bf16x8 bl = *(const bf16x8*)((const char*)VL + boff);
                #pragma unroll
                for (int r = 0; r < 2; r++) {
                    acc[r][c] = mfma16(ah[r], bh, acc[r][c]);
                    acc[r][c] = mfma16(ah[r], bl, acc[r][c]);
                    acc[r][c] = mfma16(al[r], bh, acc[r][c]);
                }
            }
        }
        __syncthreads();
    }
    #pragma unroll
    for (int r = 0; r < 2; r++)
    #pragma unroll
    for (int c = 0; c < 2; c++)
    #pragma unroll
    for (int q = 0; q < 4; q++) {
        int n = n0 + r * 16 + 4 * lg + q;
        int d = wc + c * 16 + lr;
        out[((size_t)b * 512 + n) * 128 + d] = acc[r][c][q] + Pb[d];
    }
}

extern "C" void kernel_launch(void* const* d_in, const int* in_sizes, int n_in,
                              void* d_out, int out_size, void* d_ws, size_t ws_size,
                              hipStream_t stream) {
    (void)in_sizes; (void)n_in; (void)out_size; (void)ws_size;
    const float* X  = (const float*)d_in[0];
    const void*  E  = d_in[1];
    const float* Qw = (const float*)d_in[2];
    const float* Qb = (const float*)d_in[3];
    const float* Kw = (const float*)d_in[4];
    const float* Kb = (const float*)d_in[5];
    const float* Vw = (const float*)d_in[6];
    const float* Vb = (const float*)d_in[7];
    const float* Aa = (const float*)d_in[8];
    const float* Pw = (const float*)d_in[9];
    const float* Pb = (const float*)d_in[10];
    float* out = (float*)d_out;

    char* ws = (char*)d_ws;
    size_t cur = 0;
    auto alloc = [&](size_t bytes) -> char* {
        char* p = ws + cur;
        cur += (bytes + 255) & ~(size_t)255;
        return p;
    };
    int*   flag = (int*)  alloc(4);
    u16*   WFH  = (u16*)  alloc((size_t)1280 * 128 * 2);
    u16*   WFL  = (u16*)  alloc((size_t)1280 * 128 * 2);
    float* bcat = (float*)alloc(1280 * 4);
    float* C    = (float*)alloc((size_t)16384 * 1280 * 4);
    u16*   VTH  = (u16*)  alloc((size_t)32 * 128 * 512 * 2);
    u16*   VTL  = (u16*)  alloc((size_t)32 * 128 * 512 * 2);
    float* att  = (float*)alloc((size_t)32 * 512 * 512 * 4);

    prep_kernel<<<640, 256, 0, stream>>>(Qw, Qb, Kw, Kb, Vw, Vb, Aa, Pw, WFH, WFL, bcat);
    detect_kernel<<<1, 256, 0, stream>>>((const int*)E, flag);
    gemm1_kernel<<<1024, 256, 0, stream>>>(X, WFH, WFL, bcat, C, VTH, VTL);
    scores_kernel<<<1024, 512, 0, stream>>>(C, E, flag, att);
    out_kernel<<<512, 256, 0, stream>>>(att, VTH, VTL, Pb, out);
}